// Round 1
// baseline (398.920 us; speedup 1.0000x reference)
//
#include <hip/hip_runtime.h>

typedef unsigned short u16;
using bf16x8 = __attribute__((ext_vector_type(8))) __bf16;
using f32x4  = __attribute__((ext_vector_type(4))) float;

#define SCALE 0.125f

__device__ __forceinline__ u16 f2bf(float f) {
  union { float f; unsigned int u; } x; x.f = f;
  unsigned int r = x.u + 0x7FFFu + ((x.u >> 16) & 1u);
  return (u16)(r >> 16);
}

__device__ __forceinline__ bf16x8 ld8(const u16* p) {
  return *reinterpret_cast<const bf16x8*>(p);
}

__device__ __forceinline__ void gload16(const u16* g, u16* l) {
  __builtin_amdgcn_global_load_lds(
      (const __attribute__((address_space(1))) unsigned int*)g,
      (__attribute__((address_space(3))) unsigned int*)l, 16, 0, 0);
}

__global__ void cast_f32_to_bf16(const float* __restrict__ in, u16* __restrict__ out, int n4) {
  int i = blockIdx.x * 256 + threadIdx.x;
  if (i < n4) {
    const float4 v = reinterpret_cast<const float4*>(in)[i];
    ushort4 o;
    o.x = f2bf(v.x); o.y = f2bf(v.y); o.z = f2bf(v.z); o.w = f2bf(v.w);
    reinterpret_cast<ushort4*>(out)[i] = o;
  }
}

// C[M,N] = A[M,K] @ B[N,K]^T ; A,B bf16. BF16_OUT=1: bf16 C. BF16_OUT=0: f32 C + bias.
// m97 structure: 128x128 tile, BK=32, global_load_lds w=16, 2 barriers/K-step.
template<int BF16_OUT>
__global__ __launch_bounds__(256)
void gemm_bt(const u16* __restrict__ A, const u16* __restrict__ B,
             u16* __restrict__ Cb, float* __restrict__ Cf,
             const float* __restrict__ bias, int M, int N, int K) {
  __shared__ alignas(16) u16 lds_a[128 * 32];
  __shared__ alignas(16) u16 lds_b[128 * 32];
  const int t = threadIdx.x;
  const int w = t >> 6, lane = t & 63;
  const int wr = w >> 1, wc = w & 1;
  const size_t row0 = (size_t)blockIdx.y * 128;
  const size_t col0 = (size_t)blockIdx.x * 128;

  f32x4 acc[4][4];
#pragma unroll
  for (int i = 0; i < 4; ++i)
#pragma unroll
    for (int j = 0; j < 4; ++j) acc[i][j] = {0.f, 0.f, 0.f, 0.f};

  // staging: thread t covers tile row t>>2 (issue adds 64), k-chunk (t&3)*8
  const u16* ga = A + (row0 + (t >> 2)) * K + (t & 3) * 8;
  const u16* gb = B + (col0 + (t >> 2)) * K + (t & 3) * 8;
  u16* la = lds_a + w * 512;  // wave-uniform LDS base (lane*16B implicit)
  u16* lb = lds_b + w * 512;

  const int fr = lane & 15;
  const int fk = (lane >> 4) * 8;

  for (int kt = 0; kt < K; kt += 32) {
    __syncthreads();
    gload16(ga + kt, la);
    gload16(ga + (size_t)64 * K + kt, la + 2048);
    gload16(gb + kt, lb);
    gload16(gb + (size_t)64 * K + kt, lb + 2048);
    __syncthreads();
    bf16x8 af[4], bfr[4];
#pragma unroll
    for (int i = 0; i < 4; ++i) af[i] = ld8(&lds_a[(wr * 64 + i * 16 + fr) * 32 + fk]);
#pragma unroll
    for (int j = 0; j < 4; ++j) bfr[j] = ld8(&lds_b[(wc * 64 + j * 16 + fr) * 32 + fk]);
#pragma unroll
    for (int i = 0; i < 4; ++i)
#pragma unroll
      for (int j = 0; j < 4; ++j)
        acc[i][j] = __builtin_amdgcn_mfma_f32_16x16x32_bf16(af[i], bfr[j], acc[i][j], 0, 0, 0);
  }

  const int er = (lane >> 4) * 4, ec = lane & 15;
#pragma unroll
  for (int i = 0; i < 4; ++i)
#pragma unroll
    for (int j = 0; j < 4; ++j) {
      const size_t row = row0 + wr * 64 + i * 16 + er;
      const size_t col = col0 + wc * 64 + j * 16 + ec;
#pragma unroll
      for (int r = 0; r < 4; ++r) {
        if (BF16_OUT) Cb[(row + r) * N + col] = f2bf(acc[i][j][r]);
        else          Cf[(row + r) * N + col] = acc[i][j][r] + bias[col];
      }
    }
}

// Flash attention: grid (32 qtiles, 16 heads, 4 batch), 256 threads (4 waves).
// Q tile 64 rows (16/wave, hoisted to regs), KV tiles of 64.
__global__ __launch_bounds__(256)
void flash_attn(const u16* __restrict__ Q, const u16* __restrict__ Km,
                const u16* __restrict__ V, u16* __restrict__ O) {
  const int qt = blockIdx.x, h = blockIdx.y, b = blockIdx.z;
  const int t = threadIdx.x;
  const int w = t >> 6, lane = t & 63;
  const int l16 = lane & 15, lh = lane >> 4;

  __shared__ alignas(16) u16 kt_lds[64][80];       // [key][dim]
  __shared__ alignas(16) u16 vt_lds[64][80];       // [dim][key^swz]
  __shared__ alignas(16) u16 p_lds[4][16][80];     // per-wave P

  const size_t base = ((size_t)b * 2048) * 1024 + (size_t)h * 64;

  bf16x8 qf[2];
  {
    const size_t qrow = (size_t)qt * 64 + w * 16 + l16;
    const u16* qp = Q + base + qrow * 1024 + lh * 8;
    qf[0] = ld8(qp);
    qf[1] = ld8(qp + 32);
  }

  f32x4 o_acc[4];
  float mrun[4], lrun[4];
#pragma unroll
  for (int j = 0; j < 4; ++j) o_acc[j] = {0.f, 0.f, 0.f, 0.f};
#pragma unroll
  for (int r = 0; r < 4; ++r) { mrun[r] = -1e30f; lrun[r] = 0.f; }

  const int st_r = t >> 3;        // 0..31 (key row)
  const int st_d = (t & 7) * 8;   // dim chunk

  for (int kv = 0; kv < 2048; kv += 64) {
    __syncthreads();
#pragma unroll
    for (int pass = 0; pass < 2; ++pass) {
      const int key = st_r + pass * 32;
      const u16* kp = Km + base + (size_t)(kv + key) * 1024 + st_d;
      *reinterpret_cast<uint4*>(&kt_lds[key][st_d]) = *reinterpret_cast<const uint4*>(kp);
      const u16* vp = V + base + (size_t)(kv + key) * 1024 + st_d;
      uint4 vv = *reinterpret_cast<const uint4*>(vp);
      const u16* vs = reinterpret_cast<const u16*>(&vv);
#pragma unroll
      for (int i2 = 0; i2 < 8; ++i2) {
        const int d = st_d + i2;
        vt_lds[d][key ^ (((d >> 3) & 7) << 3)] = vs[i2];  // row-dep XOR: breaks transpose write conflicts
      }
    }
    __syncthreads();

    // S = Q K^T (wave's 16 rows x 64 keys)
    f32x4 s[4];
#pragma unroll
    for (int j = 0; j < 4; ++j) {
      f32x4 acc = {0.f, 0.f, 0.f, 0.f};
#pragma unroll
      for (int ks = 0; ks < 2; ++ks) {
        bf16x8 kf = ld8(&kt_lds[j * 16 + l16][lh * 8 + ks * 32]);
        acc = __builtin_amdgcn_mfma_f32_16x16x32_bf16(qf[ks], kf, acc, 0, 0, 0);
      }
      s[j] = acc;
    }
#pragma unroll
    for (int j = 0; j < 4; ++j)
#pragma unroll
      for (int r = 0; r < 4; ++r) s[j][r] *= SCALE;

    // online softmax; row of reg r = lh*4+r, row-reduce over 16 lanes (xor 1,2,4,8)
    float rmax[4];
#pragma unroll
    for (int r = 0; r < 4; ++r)
      rmax[r] = fmaxf(fmaxf(s[0][r], s[1][r]), fmaxf(s[2][r], s[3][r]));
#pragma unroll
    for (int off = 1; off < 16; off <<= 1)
#pragma unroll
      for (int r = 0; r < 4; ++r) rmax[r] = fmaxf(rmax[r], __shfl_xor(rmax[r], off));

    float mnew[4], alpha[4], rsum[4], p[4][4];
#pragma unroll
    for (int r = 0; r < 4; ++r) {
      mnew[r] = fmaxf(mrun[r], rmax[r]);
      alpha[r] = __expf(mrun[r] - mnew[r]);
      mrun[r] = mnew[r];
      rsum[r] = 0.f;
    }
#pragma unroll
    for (int j = 0; j < 4; ++j)
#pragma unroll
      for (int r = 0; r < 4; ++r) {
        p[j][r] = __expf(s[j][r] - mnew[r]);
        rsum[r] += p[j][r];
      }
#pragma unroll
    for (int off = 1; off < 16; off <<= 1)
#pragma unroll
      for (int r = 0; r < 4; ++r) rsum[r] += __shfl_xor(rsum[r], off);
#pragma unroll
    for (int r = 0; r < 4; ++r) lrun[r] = lrun[r] * alpha[r] + rsum[r];
#pragma unroll
    for (int jd = 0; jd < 4; ++jd)
#pragma unroll
      for (int r = 0; r < 4; ++r) o_acc[jd][r] *= alpha[r];

    // P -> per-wave LDS (bf16), then PV
#pragma unroll
    for (int j = 0; j < 4; ++j)
#pragma unroll
      for (int r = 0; r < 4; ++r)
        p_lds[w][lh * 4 + r][j * 16 + l16] = f2bf(p[j][r]);
    asm volatile("s_waitcnt lgkmcnt(0)" ::: "memory");  // in-wave write->read fence

#pragma unroll
    for (int ks = 0; ks < 2; ++ks) {
      bf16x8 pf = ld8(&p_lds[w][l16][lh * 8 + ks * 32]);
#pragma unroll
      for (int jd = 0; jd < 4; ++jd) {
        const int d = jd * 16 + l16;
        bf16x8 vf = ld8(&vt_lds[d][(lh * 8 + ks * 32) ^ (((d >> 3) & 7) << 3)]);
        o_acc[jd] = __builtin_amdgcn_mfma_f32_16x16x32_bf16(pf, vf, o_acc[jd], 0, 0, 0);
      }
    }
  }

  const size_t orow0 = (size_t)b * 2048 + (size_t)qt * 64 + w * 16;
#pragma unroll
  for (int jd = 0; jd < 4; ++jd) {
    const int col = h * 64 + jd * 16 + l16;
#pragma unroll
    for (int r = 0; r < 4; ++r) {
      float val = o_acc[jd][r] / lrun[r];
      O[(orow0 + lh * 4 + r) * 1024 + col] = f2bf(val);
    }
  }
}

extern "C" void kernel_launch(void* const* d_in, const int* in_sizes, int n_in,
                              void* d_out, int out_size, void* d_ws, size_t ws_size,
                              hipStream_t stream) {
  const float* xq = (const float*)d_in[0];
  const float* xk = (const float*)d_in[1];
  const float* xv = (const float*)d_in[2];
  const float* Wq = (const float*)d_in[3];
  const float* Wk = (const float*)d_in[4];
  const float* Wv = (const float*)d_in[5];
  const float* Wo = (const float*)d_in[6];
  const float* bo = (const float*)d_in[7];
  float* out = (float*)d_out;

  const size_t X = (size_t)8192 * 1024;   // 4*2048 x 1024
  const size_t W = (size_t)1024 * 1024;

  u16* p = (u16*)d_ws;
  u16* xq_bf = p; p += X;
  u16* xk_bf = p; p += X;
  u16* xv_bf = p; p += X;
  u16* wq_bf = p; p += W;
  u16* wk_bf = p; p += W;
  u16* wv_bf = p; p += W;
  u16* wo_bf = p; p += W;
  u16* q_bf  = p; p += X;
  u16* k_bf  = p; p += X;
  u16* v_bf  = p; p += X;
  u16* attn_bf = xq_bf;  // xq_bf dead after Q projection; reuse

  dim3 blk(256);
  cast_f32_to_bf16<<<(int)(X / 4 / 256), blk, 0, stream>>>(xq, xq_bf, (int)(X / 4));
  cast_f32_to_bf16<<<(int)(X / 4 / 256), blk, 0, stream>>>(xk, xk_bf, (int)(X / 4));
  cast_f32_to_bf16<<<(int)(X / 4 / 256), blk, 0, stream>>>(xv, xv_bf, (int)(X / 4));
  cast_f32_to_bf16<<<(int)(W / 4 / 256), blk, 0, stream>>>(Wq, wq_bf, (int)(W / 4));
  cast_f32_to_bf16<<<(int)(W / 4 / 256), blk, 0, stream>>>(Wk, wk_bf, (int)(W / 4));
  cast_f32_to_bf16<<<(int)(W / 4 / 256), blk, 0, stream>>>(Wv, wv_bf, (int)(W / 4));
  cast_f32_to_bf16<<<(int)(W / 4 / 256), blk, 0, stream>>>(Wo, wo_bf, (int)(W / 4));

  dim3 gg(1024 / 128, 8192 / 128);  // (8, 64)
  gemm_bt<1><<<gg, blk, 0, stream>>>(xq_bf, wq_bf, q_bf, nullptr, nullptr, 8192, 1024, 1024);
  gemm_bt<1><<<gg, blk, 0, stream>>>(xk_bf, wk_bf, k_bf, nullptr, nullptr, 8192, 1024, 1024);
  gemm_bt<1><<<gg, blk, 0, stream>>>(xv_bf, wv_bf, v_bf, nullptr, nullptr, 8192, 1024, 1024);

  dim3 ga(32, 16, 4);
  flash_attn<<<ga, blk, 0, stream>>>(q_bf, k_bf, v_bf, attn_bf);

  gemm_bt<0><<<gg, blk, 0, stream>>>(attn_bf, wo_bf, nullptr, out, bo, 8192, 1024, 1024);
}